// Round 1
// 780.512 us; speedup vs baseline: 1.0008x; 1.0008x over previous
//
#include <hip/hip_runtime.h>

#define BB 8192
#define TT 10
#define FF 561
#define FP 576   // 561 padded to 18*32
#define HH 256
#define OO 12

typedef __attribute__((ext_vector_type(8))) __bf16 bf16x8;
typedef __attribute__((ext_vector_type(4))) float f32x4;

__device__ __forceinline__ unsigned short f2bf(float f) {
  unsigned int u = __float_as_uint(f);
  u += 0x7fffu + ((u >> 16) & 1u);   // round-to-nearest-even
  return (unsigned short)(u >> 16);
}
__device__ __forceinline__ float sigm(float x) { return 1.f / (1.f + __expf(-x)); }
__device__ __forceinline__ float tanh_fast(float x) { return 1.f - 2.f / (__expf(2.f * x) + 1.f); }

__device__ __forceinline__ void gl_lds16(const unsigned short* g, unsigned short* l) {
  __builtin_amdgcn_global_load_lds(
      (const __attribute__((address_space(1))) unsigned int*)g,
      (__attribute__((address_space(3))) unsigned int*)l, 16, 0, 0);
}

// 128x128 tile worth of MFMA from one LDS A/B buffer (BK=32)
__device__ __forceinline__ void mfma_tile(const unsigned short* as, const unsigned short* bs,
                                          int w, int quad, int l15, f32x4 (&acc)[2][8]) {
  bf16x8 af[2], bfr[8];
#pragma unroll
  for (int mt = 0; mt < 2; ++mt)
    af[mt] = *(const bf16x8*)&as[(w * 32 + mt * 16 + l15) * 32 + quad * 8];
#pragma unroll
  for (int nt = 0; nt < 8; ++nt)
    bfr[nt] = *(const bf16x8*)&bs[(nt * 16 + l15) * 32 + quad * 8];
#pragma unroll
  for (int mt = 0; mt < 2; ++mt)
#pragma unroll
    for (int nt = 0; nt < 8; ++nt)
      acc[mt][nt] = __builtin_amdgcn_mfma_f32_16x16x32_bf16(af[mt], bfr[nt], acc[mt][nt], 0, 0, 0);
}

// Convert inputs [81920,561] f32 -> bf16 zero-padded [81920,576]
__global__ void conv_inputs(const float* __restrict__ in, unsigned short* __restrict__ Ain) {
  int idx = blockIdx.x * 256 + threadIdx.x;  // over 81920*144, 4 elems each
  if (idx >= 81920 * 144) return;
  int c4 = (idx % 144) * 4;
  size_t row = idx / 144;
  const float* src = in + row * 561 + c4;
  ushort4 v;
  v.x = f2bf(c4 + 0 < 561 ? src[0] : 0.f);
  v.y = f2bf(c4 + 1 < 561 ? src[1] : 0.f);
  v.z = f2bf(c4 + 2 < 561 ? src[2] : 0.f);
  v.w = f2bf(c4 + 3 < 561 ? src[3] : 0.f);
  *(ushort4*)(Ain + row * 576 + c4) = v;
}

// Build bf16 weights:
//  Wib [256][576]: W_inp zero-padded
//  W0p/W1p [1024][512]: permuted fused [Wih|Whh];
//    out row n' -> (h=(n'>>7)*32+(n'&31), gate=(n'>>5)&3), src row = gate*256+h
//  Wob [16][256]: W_out zero-padded rows 12..15
__global__ void conv_weights(const float* __restrict__ Winp,
                             const float* __restrict__ Wih0, const float* __restrict__ Whh0,
                             const float* __restrict__ Wih1, const float* __restrict__ Whh1,
                             const float* __restrict__ Wout,
                             unsigned short* __restrict__ Wib,
                             unsigned short* __restrict__ W0p,
                             unsigned short* __restrict__ W1p,
                             unsigned short* __restrict__ Wob) {
  int idx = blockIdx.x * 256 + threadIdx.x;
  if (idx < 256 * 576) {
    int kk = idx % 576, n = idx / 576;
    Wib[idx] = f2bf(kk < 561 ? Winp[n * 561 + kk] : 0.f);
    return;
  }
  idx -= 256 * 576;
  if (idx < 1024 * 512) {
    int kk = idx % 512, np = idx / 512;
    int h = (np >> 7) * 32 + (np & 31), g = (np >> 5) & 3;
    int sr = g * 256 + h;
    float v = kk < 256 ? Wih0[sr * 256 + kk] : Whh0[sr * 256 + kk - 256];
    W0p[idx] = f2bf(v);
    return;
  }
  idx -= 1024 * 512;
  if (idx < 1024 * 512) {
    int kk = idx % 512, np = idx / 512;
    int h = (np >> 7) * 32 + (np & 31), g = (np >> 5) & 3;
    int sr = g * 256 + h;
    float v = kk < 256 ? Wih1[sr * 256 + kk] : Whh1[sr * 256 + kk - 256];
    W1p[idx] = f2bf(v);
    return;
  }
  idx -= 1024 * 512;
  if (idx < 16 * 256) {
    int kk = idx % 256, o = idx / 256;
    Wob[idx] = f2bf(o < OO ? Wout[o * 256 + kk] : 0.f);
  }
}

// xp GEMM: xp[81920,256] = Ain @ Wib^T + b_inp. M=81920 N=256 K=576.
// 1D grid 1280 blocks; XCD-aware decode: xcd=bid&7, nb paired adjacent so both
// N-halves of the same A rows run back-to-back on the same XCD (A read once from HBM).
// 2-phase double-buffered K-loop (18 tiles of BK=32).
__global__ __launch_bounds__(256, 2) void gemm_xp(
    const unsigned short* __restrict__ A, const unsigned short* __restrict__ W,
    const float* __restrict__ bias, unsigned short* __restrict__ xp) {
  __shared__ __align__(16) unsigned short As[2][128 * 32];
  __shared__ __align__(16) unsigned short Bs[2][128 * 32];
  const int tid = threadIdx.x;
  const int w = tid >> 6, lane = tid & 63, quad = lane >> 4, l15 = lane & 15;
  const int flat = blockIdx.x;
  const int xcd = flat & 7, kb = flat >> 3;     // kb in [0,160)
  const int nb = kb & 1, mb = xcd * 80 + (kb >> 1);
  const int r0 = tid >> 2, cc = (tid & 3) * 8;

  auto stage = [&](int buf, int k0) {
    gl_lds16(A + (size_t)(mb * 128 + r0) * FP + k0 + cc, &As[buf][tid * 8]);
    gl_lds16(A + (size_t)(mb * 128 + 64 + r0) * FP + k0 + cc, &As[buf][2048 + tid * 8]);
    gl_lds16(W + (size_t)(nb * 128 + r0) * FP + k0 + cc, &Bs[buf][tid * 8]);
    gl_lds16(W + (size_t)(nb * 128 + 64 + r0) * FP + k0 + cc, &Bs[buf][2048 + tid * 8]);
  };

  f32x4 acc[2][8];
#pragma unroll
  for (int i = 0; i < 2; ++i)
#pragma unroll
    for (int j = 0; j < 8; ++j) acc[i][j] = (f32x4){0.f, 0.f, 0.f, 0.f};

  stage(0, 0);
  __syncthreads();
  int cur = 0;
#pragma unroll
  for (int ks = 0; ks < 17; ++ks) {
    stage(cur ^ 1, (ks + 1) * 32);
    mfma_tile(&As[cur][0], &Bs[cur][0], w, quad, l15, acc);
    __syncthreads();   // drains vmcnt(0): next tile resident
    cur ^= 1;
  }
  mfma_tile(&As[cur][0], &Bs[cur][0], w, quad, l15, acc);

#pragma unroll
  for (int mt = 0; mt < 2; ++mt) {
    int rowb = mb * 128 + w * 32 + mt * 16 + quad * 4;
#pragma unroll
    for (int nt = 0; nt < 8; ++nt) {
      int col = nb * 128 + nt * 16 + l15;
      float bv = bias[col];
#pragma unroll
      for (int r = 0; r < 4; ++r)
        xp[(size_t)(rowb + r) * HH + col] = f2bf(acc[mt][nt][r] + bv);
    }
  }
}

// One fused LSTM-cell GEMM job: gates = [A0(K=256) | A1(K=256)] @ W^T, then cell update.
struct LstmJob {
  const unsigned short* A0; int lda0;  // first K-half source (row stride in ushorts)
  const unsigned short* A1;            // second K-half source, row stride HH
  const unsigned short* W;             // [1024][512] gate-permuted
  const float* bA; const float* bB;    // bih, bhh (original gate-major layout)
  float* cbuf;                         // f32 cell state [8192][256]
  unsigned short* hout;                // bf16 h out [8192][256]
  float* hf32; float* cf32;            // optional f32 copies (last step only)
};

// Diagonal-fused LSTM step: each block runs njobs (1 or 2) jobs back-to-back.
// Grid = 512 blocks, 2/CU. XCD-aware decode: XCD x owns mb in [8x,8x+8) for all nb,
// so A-slice + W + c-slice stay resident in that XCD's L2 across all timesteps.
// K-loop: 16 tiles of BK=32, 2-phase double-buffered; job1's first tile is
// prefetched under job0's epilogue.
__global__ __launch_bounds__(256, 2) void lstm_step(LstmJob j0, LstmJob j1, int njobs) {
  __shared__ __align__(16) unsigned short As[2][128 * 32];
  __shared__ __align__(16) unsigned short Bs[2][128 * 32];
  const int tid = threadIdx.x;
  const int w = tid >> 6, lane = tid & 63, quad = lane >> 4, l15 = lane & 15;
  const int flat = blockIdx.x;
  const int xcd = flat & 7, kb = flat >> 3;   // kb in [0,64)
  const int nb = kb >> 3, mb = xcd * 8 + (kb & 7);
  const int r0 = tid >> 2, cc = (tid & 3) * 8;

  auto stage = [&](const LstmJob& J, int buf, int k0) {
    const unsigned short* Asrc; int ldA, kk;
    if (k0 < 256) { Asrc = J.A0; ldA = J.lda0; kk = k0; }
    else          { Asrc = J.A1; ldA = HH;     kk = k0 - 256; }
    gl_lds16(Asrc + (size_t)(mb * 128 + r0) * ldA + kk + cc, &As[buf][tid * 8]);
    gl_lds16(Asrc + (size_t)(mb * 128 + 64 + r0) * ldA + kk + cc, &As[buf][2048 + tid * 8]);
    gl_lds16(J.W + (size_t)(nb * 128 + r0) * 512 + k0 + cc, &Bs[buf][tid * 8]);
    gl_lds16(J.W + (size_t)(nb * 128 + 64 + r0) * 512 + k0 + cc, &Bs[buf][2048 + tid * 8]);
  };

  stage(j0, 0, 0);   // prologue: first tile of job 0 in flight

  for (int job = 0; job < njobs; ++job) {
    const LstmJob J = job ? j1 : j0;
    f32x4 acc[2][8];
#pragma unroll
    for (int i = 0; i < 2; ++i)
#pragma unroll
      for (int j = 0; j < 8; ++j) acc[i][j] = (f32x4){0.f, 0.f, 0.f, 0.f};

    __syncthreads();   // this job's tile 0 resident (vmcnt drained by barrier)
    int cur = 0;
#pragma unroll
    for (int ks = 0; ks < 15; ++ks) {
      stage(J, cur ^ 1, (ks + 1) * 32);
      mfma_tile(&As[cur][0], &Bs[cur][0], w, quad, l15, acc);
      __syncthreads();   // drains vmcnt(0): tile ks+1 resident
      cur ^= 1;
    }
    mfma_tile(&As[cur][0], &Bs[cur][0], w, quad, l15, acc);   // tile 15

    if (job + 1 < njobs) stage(j1, 0, 0);   // prefetch next job under epilogue

    // cell update: nb's 128 gate-cols = gates {i,f,g,o} x 2 h-halves of h-block nb
#pragma unroll
    for (int hb = 0; hb < 2; ++hb) {
      const int hg = nb * 32 + hb * 16 + l15;
      const float bI = J.bA[hg] + J.bB[hg];
      const float bF = J.bA[256 + hg] + J.bB[256 + hg];
      const float bG = J.bA[512 + hg] + J.bB[512 + hg];
      const float bO = J.bA[768 + hg] + J.bB[768 + hg];
#pragma unroll
      for (int mt = 0; mt < 2; ++mt) {
        const int rowb = mb * 128 + w * 32 + mt * 16 + quad * 4;
#pragma unroll
        for (int r = 0; r < 4; ++r) {
          const size_t idx = (size_t)(rowb + r) * HH + hg;
          const float xi = acc[mt][0 + hb][r] + bI;
          const float xf = acc[mt][2 + hb][r] + bF;
          const float xg = acc[mt][4 + hb][r] + bG;
          const float xo = acc[mt][6 + hb][r] + bO;
          const float c_old = J.cbuf[idx];
          const float cn = sigm(xf) * c_old + sigm(xi) * tanh_fast(xg);
          const float hn = sigm(xo) * tanh_fast(cn);
          J.cbuf[idx] = cn;
          J.hout[idx] = f2bf(hn);
          if (J.hf32) { J.hf32[idx] = hn; J.cf32[idx] = cn; }
        }
      }
    }
  }
}

// Output projection as MFMA GEMM: out[m=t*B+b][o] = hs[m+B][:] . Wob[o][:] + bout[o]
__global__ __launch_bounds__(256) void out_gemm_mfma(
    const unsigned short* __restrict__ hs,   // [(T+1)*B][HH], slots 1..T hold h1(t)
    const unsigned short* __restrict__ Wob,  // [16][HH] bf16, rows 12..15 zero
    const float* __restrict__ bout,
    float* __restrict__ out) {               // [B][T][OO]
  const int tid = threadIdx.x;
  const int w = tid >> 6, lane = tid & 63, quad = lane >> 4, l15 = lane & 15;
  const int m0 = blockIdx.x * 64 + w * 16;   // m = t*B + b
  const unsigned short* arow = hs + (size_t)(m0 + l15 + BB) * HH + quad * 8;
  const unsigned short* brow = Wob + l15 * HH + quad * 8;
  f32x4 acc = (f32x4){0.f, 0.f, 0.f, 0.f};
#pragma unroll
  for (int k0 = 0; k0 < 8; ++k0) {
    bf16x8 a = *(const bf16x8*)(arow + k0 * 32);
    bf16x8 b = *(const bf16x8*)(brow + k0 * 32);
    acc = __builtin_amdgcn_mfma_f32_16x16x32_bf16(a, b, acc, 0, 0, 0);
  }
  const int o = l15;
  if (o < OO) {
    float bv = bout[o];
#pragma unroll
    for (int r = 0; r < 4; ++r) {
      int m = m0 + quad * 4 + r;
      int b = m & (BB - 1);
      int t = m >> 13;                       // m / BB
      out[((size_t)b * TT + t) * OO + o] = acc[r] + bv;
    }
  }
}

extern "C" void kernel_launch(void* const* d_in, const int* in_sizes, int n_in,
                              void* d_out, int out_size, void* d_ws, size_t ws_size,
                              hipStream_t stream) {
  const float* inputs = (const float*)d_in[0];
  const float* W_inp  = (const float*)d_in[1];
  const float* b_inp  = (const float*)d_in[2];
  const float* Wih0   = (const float*)d_in[3];
  const float* Whh0   = (const float*)d_in[4];
  const float* bih0   = (const float*)d_in[5];
  const float* bhh0   = (const float*)d_in[6];
  const float* Wih1   = (const float*)d_in[7];
  const float* Whh1   = (const float*)d_in[8];
  const float* bih1   = (const float*)d_in[9];
  const float* bhh1   = (const float*)d_in[10];
  const float* W_out  = (const float*)d_in[11];
  const float* b_out  = (const float*)d_in[12];
  float* out = (float*)d_out;

  char* ws = (char*)d_ws;
  size_t off = 0;
  auto alloc = [&](size_t bytes) {
    char* p = ws + off;
    off += (bytes + 255) & ~(size_t)255;
    return p;
  };
  unsigned short* Ain = (unsigned short*)alloc((size_t)81920 * FP * 2);
  unsigned short* xp  = (unsigned short*)alloc((size_t)81920 * HH * 2);
  unsigned short* Wib = (unsigned short*)alloc((size_t)256 * FP * 2);
  unsigned short* W0p = (unsigned short*)alloc((size_t)1024 * 512 * 2);
  unsigned short* W1p = (unsigned short*)alloc((size_t)1024 * 512 * 2);
  unsigned short* Wob = (unsigned short*)alloc((size_t)16 * HH * 2);
  unsigned short* h0s = (unsigned short*)alloc((size_t)2 * BB * HH * 2);   // ping-pong
  unsigned short* hs  = (unsigned short*)alloc((size_t)(TT + 1) * BB * HH * 2); // slot0=zeros
  float* c0 = (float*)alloc((size_t)BB * HH * 4);
  float* c1 = (float*)alloc((size_t)BB * HH * 4);

  // zero-init states (ws is re-poisoned 0xAA before every timed launch)
  hipMemsetAsync(h0s, 0, (size_t)BB * HH * 2, stream);   // slot 0 only
  hipMemsetAsync(hs, 0, (size_t)BB * HH * 2, stream);    // slot 0 only
  hipMemsetAsync(c0, 0, (size_t)BB * HH * 4, stream);
  hipMemsetAsync(c1, 0, (size_t)BB * HH * 4, stream);

  conv_inputs<<<(81920 * 144 + 255) / 256, 256, 0, stream>>>(inputs, Ain);
  {
    int nthr = 256 * 576 + 2 * 1024 * 512 + 16 * 256;
    conv_weights<<<(nthr + 255) / 256, 256, 0, stream>>>(W_inp, Wih0, Whh0, Wih1, Whh1,
                                                         W_out, Wib, W0p, W1p, Wob);
  }

  gemm_xp<<<1280, 256, 0, stream>>>(Ain, Wib, b_inp, xp);

  float* hn_out = out + (size_t)BB * TT * OO;       // h_n [2][B][H]
  float* cn_out = hn_out + (size_t)2 * BB * HH;     // c_n [2][B][H]

  // Diagonal schedule: step s runs L0(t=s) and L1(t=s-1) in one launch.
  // L0(s) reads h0s[s&1], writes h0s[(s+1)&1]; L1(s-1) reads h0s[s&1] + hs[s-1],
  // writes hs[s] -> no intra-launch hazards.
  for (int s = 0; s <= TT; ++s) {
    LstmJob jobs[2];
    int nj = 0;
    if (s < TT) {          // layer 0, t = s
      int t = s;
      jobs[nj++] = LstmJob{
          xp + (size_t)t * HH, TT * HH,
          h0s + (size_t)(t & 1) * BB * HH,
          W0p, bih0, bhh0, c0,
          h0s + (size_t)((t + 1) & 1) * BB * HH,
          (t == TT - 1) ? hn_out : nullptr,
          (t == TT - 1) ? cn_out : nullptr};
    }
    if (s > 0) {           // layer 1, t = s-1
      int t = s - 1;
      jobs[nj++] = LstmJob{
          h0s + (size_t)((t + 1) & 1) * BB * HH, HH,
          hs + (size_t)t * BB * HH,
          W1p, bih1, bhh1, c1,
          hs + (size_t)(t + 1) * BB * HH,
          (t == TT - 1) ? hn_out + (size_t)BB * HH : nullptr,
          (t == TT - 1) ? cn_out + (size_t)BB * HH : nullptr};
    }
    lstm_step<<<512, 256, 0, stream>>>(jobs[0], nj == 2 ? jobs[1] : jobs[0], nj);
  }

  out_gemm_mfma<<<1280, 256, 0, stream>>>(hs, Wob, b_out, out);
}